// Round 4
// baseline (193.388 us; speedup 1.0000x reference)
//
#include <hip/hip_runtime.h>
#include <stdint.h>
#include <stddef.h>

#define B_ROWS 8192
#define NX 2048
#define NH 512
#define NY 1024

// prep kernel block split: elementwise cast blocks, then wq blocks
#define X_ELEMS (B_ROWS * NX)                 // 16777216 (relu+cast)
#define EW_ELEMS (X_ELEMS + NH * NX)          // + 1048576 (plain cast)
#define EW_BLOCKS (EW_ELEMS / (8 * 256))      // 8704
#define WQ_BLOCKS (NY / 4)                    // 256

typedef __attribute__((ext_vector_type(8))) short bf16x8;
typedef __attribute__((ext_vector_type(4))) float f32x4;

static __device__ __forceinline__ unsigned short f2bf(float f) {
    union { float f; unsigned int u; } c; c.f = f;
    unsigned int r = 0x7FFFu + ((c.u >> 16) & 1u);
    return (unsigned short)((c.u + r) >> 16);
}

static __device__ __forceinline__ void glld16(const void* g, void* l) {
    __builtin_amdgcn_global_load_lds(
        (const __attribute__((address_space(1))) unsigned int*)g,
        (__attribute__((address_space(3))) unsigned int*)l, 16, 0, 0);
}

// ---------------- prep: relu(x)->bf16, W_fc->bf16, W_q->bf16+rowsq, hsq=0 ----------------
__global__ __launch_bounds__(256) void prep_kernel(const float* __restrict__ x,
                                                   const float* __restrict__ wfc,
                                                   const float* __restrict__ wq,
                                                   unsigned short* __restrict__ xb,
                                                   unsigned short* __restrict__ wfcb,
                                                   unsigned short* __restrict__ wqb,
                                                   float* __restrict__ wqsq,
                                                   float* __restrict__ hsq) {
    const int bid = blockIdx.x;
    const int tid = threadIdx.x;
    if (bid < EW_BLOCKS) {
        size_t idx = ((size_t)bid * 256 + tid) * 8;
        if (idx < (size_t)X_ELEMS) {
            float4 a = *(const float4*)&x[idx];
            float4 b = *(const float4*)&x[idx + 4];
            bf16x8 o;
            o[0] = (short)f2bf(fmaxf(a.x, 0.f)); o[1] = (short)f2bf(fmaxf(a.y, 0.f));
            o[2] = (short)f2bf(fmaxf(a.z, 0.f)); o[3] = (short)f2bf(fmaxf(a.w, 0.f));
            o[4] = (short)f2bf(fmaxf(b.x, 0.f)); o[5] = (short)f2bf(fmaxf(b.y, 0.f));
            o[6] = (short)f2bf(fmaxf(b.z, 0.f)); o[7] = (short)f2bf(fmaxf(b.w, 0.f));
            *(bf16x8*)&xb[idx] = o;
        } else {
            size_t off = idx - X_ELEMS;
            float4 a = *(const float4*)&wfc[off];
            float4 b = *(const float4*)&wfc[off + 4];
            bf16x8 o;
            o[0] = (short)f2bf(a.x); o[1] = (short)f2bf(a.y);
            o[2] = (short)f2bf(a.z); o[3] = (short)f2bf(a.w);
            o[4] = (short)f2bf(b.x); o[5] = (short)f2bf(b.y);
            o[6] = (short)f2bf(b.z); o[7] = (short)f2bf(b.w);
            *(bf16x8*)&wfcb[off] = o;
        }
    } else {
        const int b2 = bid - EW_BLOCKS;        // 0..255
        const int lane = tid & 63;
        const int row = b2 * 4 + (tid >> 6);
        const float* p = wq + (size_t)row * NH + lane * 8;
        float4 a = *(const float4*)p;
        float4 b = *(const float4*)(p + 4);
        bf16x8 o;
        o[0] = (short)f2bf(a.x); o[1] = (short)f2bf(a.y);
        o[2] = (short)f2bf(a.z); o[3] = (short)f2bf(a.w);
        o[4] = (short)f2bf(b.x); o[5] = (short)f2bf(b.y);
        o[6] = (short)f2bf(b.z); o[7] = (short)f2bf(b.w);
        *(bf16x8*)&wqb[(size_t)row * NH + lane * 8] = o;
        float s = a.x*a.x + a.y*a.y + a.z*a.z + a.w*a.w
                + b.x*b.x + b.y*b.y + b.z*b.z + b.w*b.w;
        #pragma unroll
        for (int off = 32; off > 0; off >>= 1) s += __shfl_xor(s, off);
        if (lane == 0) wqsq[row] = s;
        if (tid < 32) hsq[b2 * 32 + tid] = 0.0f;   // zero-init for gemm1 atomics
    }
}

// ---------------- GEMM1: h = relu(xb @ wfcb^T + b) -> bf16, fused ||h||^2 ----------------
// 128 threads = 2 waves; tile 64(M) x 128(N); waves split N; wave-tile 64x64 (acc 4x4).
// A: direct-to-register bf16 fragment loads (no LDS, no barrier dependency).
// B: LDS double-buffered, BK=128 (two swizzled 64-halves), ONE barrier per iter:
//    stage(k+1) issued after the barrier -> its vmcnt drain happens a full
//    compute-phase later at the next barrier (near-zero stall).
__global__ __launch_bounds__(128, 1) void gemm1_kernel(const unsigned short* __restrict__ xb,
                                                       const unsigned short* __restrict__ wfcb,
                                                       const float* __restrict__ b_fc,
                                                       unsigned short* __restrict__ hb,
                                                       float* __restrict__ hsq) {
    __shared__ unsigned short Bs[2 * 2 * 128 * 64];   // [buf][t][128 rows][64 k] = 64 KiB

    const int tid = threadIdx.x;
    const int lane = tid & 63;
    const int wave = tid >> 6;          // 0..1
    const int quad = lane >> 4;
    const int r = lane & 15;

    // XCD-aware swizzle: bid = 32a + 8b + c (c=XCD slot) -> m-tile = 16c + a, n-tile = b
    const int bid = blockIdx.x;                       // 0..511
    const int n0 = ((bid >> 3) & 3) * 128;
    const int m0 = (((bid & 7) << 4) | (bid >> 5)) * 64;

    f32x4 acc[4][4];
    #pragma unroll
    for (int i = 0; i < 4; ++i)
        #pragma unroll
        for (int j = 0; j < 4; ++j) acc[i][j] = (f32x4)(0.0f);

    const int lrow = lane >> 3;
    const int gch = (lane & 7) ^ lrow;
    const char* wfB = (const char*)wfcb;
    char* BsB = (char*)Bs;
    const int xk = r & 7;

    auto stage = [&](int buf, int k0) {
        #pragma unroll
        for (int t = 0; t < 2; ++t) {
            #pragma unroll
            for (int c = 0; c < 8; ++c) {
                int R0 = wave * 64 + c * 8;
                glld16(wfB + (size_t)(n0 + R0 + lrow) * (NX * 2) + (k0 + t * 64) * 2 + gch * 16,
                       BsB + buf * 32768 + t * 16384 + R0 * 128);
            }
        }
    };

    stage(0, 0);
    for (int it = 0; it < NX / 128; ++it) {
        const int k0 = it * 128;
        __syncthreads();                       // drains stage(it) issued last iter
        if (it + 1 < NX / 128) stage((it + 1) & 1, k0 + 128);
        const char* bufp = BsB + (it & 1) * 32768;
        #pragma unroll
        for (int t = 0; t < 2; ++t) {
            #pragma unroll
            for (int s = 0; s < 2; ++s) {
                const int ch = ((s * 4 + quad) ^ xk) * 16;
                bf16x8 af[4], bfv[4];
                #pragma unroll
                for (int i = 0; i < 4; ++i)
                    af[i] = *(const bf16x8*)&xb[(size_t)(m0 + i * 16 + r) * NX + k0 + (t * 2 + s) * 32 + quad * 8];
                #pragma unroll
                for (int j = 0; j < 4; ++j)
                    bfv[j] = *(const bf16x8*)(bufp + t * 16384 + (wave * 64 + j * 16 + r) * 128 + ch);
                #pragma unroll
                for (int i = 0; i < 4; ++i)
                    #pragma unroll
                    for (int j = 0; j < 4; ++j)
                        acc[i][j] = __builtin_amdgcn_mfma_f32_16x16x32_bf16(af[i], bfv[j], acc[i][j], 0, 0, 0);
            }
        }
    }

    float p[4][4];
    #pragma unroll
    for (int i = 0; i < 4; ++i)
        #pragma unroll
        for (int rr = 0; rr < 4; ++rr) p[i][rr] = 0.0f;

    #pragma unroll
    for (int i = 0; i < 4; ++i) {
        #pragma unroll
        for (int j = 0; j < 4; ++j) {
            int col = n0 + wave * 64 + j * 16 + r;
            float bias = b_fc[col];
            #pragma unroll
            for (int rr = 0; rr < 4; ++rr) {
                int row = m0 + i * 16 + quad * 4 + rr;
                float v = fmaxf(acc[i][j][rr] + bias, 0.0f);
                hb[(size_t)row * NH + col] = f2bf(v);
                p[i][rr] += v * v;
            }
        }
    }
    #pragma unroll
    for (int mask = 1; mask < 16; mask <<= 1) {
        #pragma unroll
        for (int i = 0; i < 4; ++i)
            #pragma unroll
            for (int rr = 0; rr < 4; ++rr)
                p[i][rr] += __shfl_xor(p[i][rr], mask);
    }
    if (r == 0) {
        #pragma unroll
        for (int i = 0; i < 4; ++i)
            #pragma unroll
            for (int rr = 0; rr < 4; ++rr)
                atomicAdd(&hsq[m0 + i * 16 + quad * 4 + rr], p[i][rr]);
    }
}

// ---------------- GEMM2 + distance + t ----------------
// 256 threads = 4 waves 2x2; tile 128x128; wave-tile 64x64 (acc 4x4).
// BK=64, A+B LDS double-buffered, one barrier per iter (8 iters).
__global__ __launch_bounds__(256, 2) void gemm2_kernel(const unsigned short* __restrict__ hb,
                                                       const unsigned short* __restrict__ wqb,
                                                       const float* __restrict__ hsq,
                                                       const float* __restrict__ wqsq,
                                                       float* __restrict__ out) {
    __shared__ unsigned short As[2 * 128 * 64];   // [buf][128][64] = 32 KiB
    __shared__ unsigned short Bs[2 * 128 * 64];   // 32 KiB

    const int tid = threadIdx.x;
    const int lane = tid & 63;
    const int wave = tid >> 6;
    const int wm = wave >> 1, wn = wave & 1;
    const int quad = lane >> 4;
    const int r = lane & 15;

    // bid = 64a + 8b + c -> m-tile = 8c + a (0..63), n-tile = b (0..7)
    const int bid = blockIdx.x;                   // 0..511
    const int n0 = ((bid >> 3) & 7) * 128;
    const int m0 = (((bid & 7) << 3) | (bid >> 6)) * 128;

    f32x4 acc[4][4];
    #pragma unroll
    for (int i = 0; i < 4; ++i)
        #pragma unroll
        for (int j = 0; j < 4; ++j) acc[i][j] = (f32x4)(0.0f);

    const int lrow = lane >> 3;
    const int gch = (lane & 7) ^ lrow;
    const char* hbB = (const char*)hb;
    const char* wqB = (const char*)wqb;
    char* AsB = (char*)As;
    char* BsB = (char*)Bs;
    const int xk = r & 7;

    auto stage = [&](int buf, int k0) {
        #pragma unroll
        for (int c = 0; c < 4; ++c) {
            int R0 = wave * 32 + c * 8;
            glld16(hbB + (size_t)(m0 + R0 + lrow) * (NH * 2) + k0 * 2 + gch * 16,
                   AsB + buf * 16384 + R0 * 128);
            glld16(wqB + (size_t)(n0 + R0 + lrow) * (NH * 2) + k0 * 2 + gch * 16,
                   BsB + buf * 16384 + R0 * 128);
        }
    };

    stage(0, 0);
    for (int it = 0; it < NH / 64; ++it) {
        const int k0 = it * 64;
        __syncthreads();
        if (it + 1 < NH / 64) stage((it + 1) & 1, k0 + 64);
        const char* ap = AsB + (it & 1) * 16384 + (wm * 64 + r) * 128;
        const char* bp = BsB + (it & 1) * 16384 + (wn * 64 + r) * 128;
        #pragma unroll
        for (int s = 0; s < 2; ++s) {
            const int ch = ((s * 4 + quad) ^ xk) * 16;
            bf16x8 af[4], bfv[4];
            #pragma unroll
            for (int i = 0; i < 4; ++i) af[i] = *(const bf16x8*)(ap + i * 16 * 128 + ch);
            #pragma unroll
            for (int j = 0; j < 4; ++j) bfv[j] = *(const bf16x8*)(bp + j * 16 * 128 + ch);
            #pragma unroll
            for (int i = 0; i < 4; ++i)
                #pragma unroll
                for (int j = 0; j < 4; ++j)
                    acc[i][j] = __builtin_amdgcn_mfma_f32_16x16x32_bf16(af[i], bfv[j], acc[i][j], 0, 0, 0);
        }
    }

    float hs[4][4];
    #pragma unroll
    for (int i = 0; i < 4; ++i)
        #pragma unroll
        for (int rr = 0; rr < 4; ++rr)
            hs[i][rr] = hsq[m0 + wm * 64 + i * 16 + quad * 4 + rr];

    #pragma unroll
    for (int i = 0; i < 4; ++i) {
        #pragma unroll
        for (int j = 0; j < 4; ++j) {
            int col = n0 + wn * 64 + j * 16 + r;
            float wq = wqsq[col];
            #pragma unroll
            for (int rr = 0; rr < 4; ++rr) {
                int row = m0 + wm * 64 + i * 16 + quad * 4 + rr;
                float d = hs[i][rr] - 2.0f * acc[i][j][rr] + wq;
                d = fmaxf(d, 0.0f);
                out[(size_t)row * NY + col] = -__logf(1.0f + d);
            }
        }
    }
}

// ---------------- per-row logsumexp (no max pass: t <= 0 so exp is safe) ----------------
__global__ __launch_bounds__(256) void lse_kernel(float* __restrict__ out) {
    __shared__ float reds[4];
    const int tid = threadIdx.x;
    const int lane = tid & 63;
    const int wave = tid >> 6;
    float* p = out + (size_t)blockIdx.x * NY;
    float4 v = ((const float4*)p)[tid];
    float s = __expf(v.x) + __expf(v.y) + __expf(v.z) + __expf(v.w);
    #pragma unroll
    for (int off = 32; off > 0; off >>= 1) s += __shfl_xor(s, off);
    if (lane == 0) reds[wave] = s;
    __syncthreads();
    float lse = __logf(reds[0] + reds[1] + reds[2] + reds[3]);
    v.x -= lse; v.y -= lse; v.z -= lse; v.w -= lse;
    ((float4*)p)[tid] = v;
}

extern "C" void kernel_launch(void* const* d_in, const int* in_sizes, int n_in,
                              void* d_out, int out_size, void* d_ws, size_t ws_size,
                              hipStream_t stream) {
    const float* x    = (const float*)d_in[0];
    const float* W_fc = (const float*)d_in[1];
    const float* b_fc = (const float*)d_in[2];
    const float* W_q  = (const float*)d_in[3];
    float* out = (float*)d_out;

    char* ws = (char*)d_ws;
    unsigned short* xb   = (unsigned short*)(ws);                        // 32 MiB
    unsigned short* wfcb = (unsigned short*)(ws + 33554432);             // 2 MiB
    unsigned short* wqb  = (unsigned short*)(ws + 35651584);             // 1 MiB
    float*          wqsq = (float*)(ws + 36700160);                      // 4 KiB
    unsigned short* hb   = (unsigned short*)(ws + 36704256);             // 8 MiB
    float*          hsq  = (float*)(ws + 45092864);                      // 32 KiB

    prep_kernel<<<EW_BLOCKS + WQ_BLOCKS, 256, 0, stream>>>(x, W_fc, W_q, xb, wfcb, wqb, wqsq, hsq);
    gemm1_kernel<<<512, 128, 0, stream>>>(xb, wfcb, b_fc, hb, hsq);
    gemm2_kernel<<<512, 256, 0, stream>>>(hb, wqb, hsq, wqsq, out);
    lse_kernel<<<B_ROWS, 256, 0, stream>>>(out);
}

// Round 5
// 169.548 us; speedup vs baseline: 1.1406x; 1.1406x over previous
//
#include <hip/hip_runtime.h>
#include <stdint.h>
#include <stddef.h>

#define B_ROWS 8192
#define NX 2048
#define NH 512
#define NY 1024

// prep kernel block split: elementwise cast blocks, then wq blocks
#define X_ELEMS (B_ROWS * NX)                 // 16777216 (relu+cast)
#define EW_ELEMS (X_ELEMS + NH * NX)          // + 1048576 (plain cast)
#define EW_BLOCKS (EW_ELEMS / (8 * 256))      // 8704
#define WQ_BLOCKS (NY / 4)                    // 256

typedef __attribute__((ext_vector_type(8))) short bf16x8;
typedef __attribute__((ext_vector_type(4))) float f32x4;

static __device__ __forceinline__ unsigned short f2bf(float f) {
    union { float f; unsigned int u; } c; c.f = f;
    unsigned int r = 0x7FFFu + ((c.u >> 16) & 1u);
    return (unsigned short)((c.u + r) >> 16);
}

static __device__ __forceinline__ void glld16(const void* g, void* l) {
    __builtin_amdgcn_global_load_lds(
        (const __attribute__((address_space(1))) unsigned int*)g,
        (__attribute__((address_space(3))) unsigned int*)l, 16, 0, 0);
}

// ---------------- prep: relu(x)->bf16, W_fc->bf16, W_q->bf16+rowsq ----------------
__global__ __launch_bounds__(256) void prep_kernel(const float* __restrict__ x,
                                                   const float* __restrict__ wfc,
                                                   const float* __restrict__ wq,
                                                   unsigned short* __restrict__ xb,
                                                   unsigned short* __restrict__ wfcb,
                                                   unsigned short* __restrict__ wqb,
                                                   float* __restrict__ wqsq) {
    const int bid = blockIdx.x;
    const int tid = threadIdx.x;
    if (bid < EW_BLOCKS) {
        size_t idx = ((size_t)bid * 256 + tid) * 8;
        if (idx < (size_t)X_ELEMS) {
            float4 a = *(const float4*)&x[idx];
            float4 b = *(const float4*)&x[idx + 4];
            bf16x8 o;
            o[0] = (short)f2bf(fmaxf(a.x, 0.f)); o[1] = (short)f2bf(fmaxf(a.y, 0.f));
            o[2] = (short)f2bf(fmaxf(a.z, 0.f)); o[3] = (short)f2bf(fmaxf(a.w, 0.f));
            o[4] = (short)f2bf(fmaxf(b.x, 0.f)); o[5] = (short)f2bf(fmaxf(b.y, 0.f));
            o[6] = (short)f2bf(fmaxf(b.z, 0.f)); o[7] = (short)f2bf(fmaxf(b.w, 0.f));
            *(bf16x8*)&xb[idx] = o;
        } else {
            size_t off = idx - X_ELEMS;
            float4 a = *(const float4*)&wfc[off];
            float4 b = *(const float4*)&wfc[off + 4];
            bf16x8 o;
            o[0] = (short)f2bf(a.x); o[1] = (short)f2bf(a.y);
            o[2] = (short)f2bf(a.z); o[3] = (short)f2bf(a.w);
            o[4] = (short)f2bf(b.x); o[5] = (short)f2bf(b.y);
            o[6] = (short)f2bf(b.z); o[7] = (short)f2bf(b.w);
            *(bf16x8*)&wfcb[off] = o;
        }
    } else {
        const int b2 = bid - EW_BLOCKS;        // 0..255
        const int lane = tid & 63;
        const int row = b2 * 4 + (tid >> 6);
        const float* p = wq + (size_t)row * NH + lane * 8;
        float4 a = *(const float4*)p;
        float4 b = *(const float4*)(p + 4);
        bf16x8 o;
        o[0] = (short)f2bf(a.x); o[1] = (short)f2bf(a.y);
        o[2] = (short)f2bf(a.z); o[3] = (short)f2bf(a.w);
        o[4] = (short)f2bf(b.x); o[5] = (short)f2bf(b.y);
        o[6] = (short)f2bf(b.z); o[7] = (short)f2bf(b.w);
        *(bf16x8*)&wqb[(size_t)row * NH + lane * 8] = o;
        float s = a.x*a.x + a.y*a.y + a.z*a.z + a.w*a.w
                + b.x*b.x + b.y*b.y + b.z*b.z + b.w*b.w;
        #pragma unroll
        for (int off = 32; off > 0; off >>= 1) s += __shfl_xor(s, off);
        if (lane == 0) wqsq[row] = s;
    }
}

// ---------------- GEMM1 (split-K=2): partial[kh] = xb @ wfcb^T over half of K ----------------
// 256 threads = 4 waves 2x2; tile 128(M)x128(N); wave-tile 64x64 (acc 4x4).
// BK=64, A+B LDS double-buffered, one barrier per iter (16 iters over K=1024).
// Partials written fp32 into d_out used as scratch (2 x 16 MiB).
__global__ __launch_bounds__(256, 2) void gemm1_kernel(const unsigned short* __restrict__ xb,
                                                       const unsigned short* __restrict__ wfcb,
                                                       float* __restrict__ partial) {
    __shared__ unsigned short As[2 * 128 * 64];   // 32 KiB
    __shared__ unsigned short Bs[2 * 128 * 64];   // 32 KiB

    const int tid = threadIdx.x;
    const int lane = tid & 63;
    const int wave = tid >> 6;
    const int wm = wave >> 1, wn = wave & 1;
    const int quad = lane >> 4;
    const int r = lane & 15;

    // bid bits: [2:0]->XCD slot (mt high), [4:3]->nt, [5]->kh, [8:6]->mt low
    const int bid = blockIdx.x;                   // 0..511
    const int n0 = ((bid >> 3) & 3) * 128;
    const int kh = (bid >> 5) & 1;
    const int m0 = (((bid & 7) << 3) | (bid >> 6)) * 128;
    const int kbase = kh * (NX / 2);

    f32x4 acc[4][4];
    #pragma unroll
    for (int i = 0; i < 4; ++i)
        #pragma unroll
        for (int j = 0; j < 4; ++j) acc[i][j] = (f32x4)(0.0f);

    const int lrow = lane >> 3;
    const int gch = (lane & 7) ^ lrow;
    const char* xbB = (const char*)xb;
    const char* wfB = (const char*)wfcb;
    char* AsB = (char*)As;
    char* BsB = (char*)Bs;
    const int xk = r & 7;

    auto stage = [&](int buf, int k0) {
        #pragma unroll
        for (int c = 0; c < 4; ++c) {
            int R0 = wave * 32 + c * 8;
            glld16(xbB + (size_t)(m0 + R0 + lrow) * (NX * 2) + k0 * 2 + gch * 16,
                   AsB + buf * 16384 + R0 * 128);
            glld16(wfB + (size_t)(n0 + R0 + lrow) * (NX * 2) + k0 * 2 + gch * 16,
                   BsB + buf * 16384 + R0 * 128);
        }
    };

    stage(0, kbase);
    #pragma unroll 1
    for (int it = 0; it < 16; ++it) {
        const int k0 = kbase + it * 64;
        __syncthreads();
        if (it + 1 < 16) stage((it + 1) & 1, k0 + 64);
        const char* ap = AsB + (it & 1) * 16384 + (wm * 64 + r) * 128;
        const char* bp = BsB + (it & 1) * 16384 + (wn * 64 + r) * 128;
        #pragma unroll
        for (int s = 0; s < 2; ++s) {
            const int ch = ((s * 4 + quad) ^ xk) * 16;
            bf16x8 af[4], bfv[4];
            #pragma unroll
            for (int i = 0; i < 4; ++i) af[i] = *(const bf16x8*)(ap + i * 16 * 128 + ch);
            #pragma unroll
            for (int j = 0; j < 4; ++j) bfv[j] = *(const bf16x8*)(bp + j * 16 * 128 + ch);
            #pragma unroll
            for (int i = 0; i < 4; ++i)
                #pragma unroll
                for (int j = 0; j < 4; ++j)
                    acc[i][j] = __builtin_amdgcn_mfma_f32_16x16x32_bf16(af[i], bfv[j], acc[i][j], 0, 0, 0);
        }
    }

    float* pout = partial + (size_t)kh * (B_ROWS * NH);
    #pragma unroll
    for (int i = 0; i < 4; ++i) {
        #pragma unroll
        for (int j = 0; j < 4; ++j) {
            int col = n0 + wn * 64 + j * 16 + r;
            #pragma unroll
            for (int rr = 0; rr < 4; ++rr) {
                int row = m0 + wm * 64 + i * 16 + quad * 4 + rr;
                pout[(size_t)row * NH + col] = acc[i][j][rr];
            }
        }
    }
}

// ---------------- reduce: h = relu(p0 + p1 + bias) -> bf16 hb, + hsq ----------------
// one wave per row (NH=512 -> 8 floats/lane), 4 rows per block
__global__ __launch_bounds__(256) void reduce_kernel(const float* __restrict__ partial,
                                                     const float* __restrict__ b_fc,
                                                     unsigned short* __restrict__ hb,
                                                     float* __restrict__ hsq) {
    const int tid = threadIdx.x;
    const int lane = tid & 63;
    const int row = blockIdx.x * 4 + (tid >> 6);
    const int c0 = lane * 8;
    const float* p0 = partial + (size_t)row * NH + c0;
    const float* p1 = partial + (size_t)(B_ROWS * NH) + (size_t)row * NH + c0;
    float4 a0 = *(const float4*)p0;
    float4 a1 = *(const float4*)(p0 + 4);
    float4 b0 = *(const float4*)p1;
    float4 b1 = *(const float4*)(p1 + 4);
    float4 f0 = *(const float4*)&b_fc[c0];
    float4 f1 = *(const float4*)&b_fc[c0 + 4];
    float h[8];
    h[0] = fmaxf(a0.x + b0.x + f0.x, 0.f); h[1] = fmaxf(a0.y + b0.y + f0.y, 0.f);
    h[2] = fmaxf(a0.z + b0.z + f0.z, 0.f); h[3] = fmaxf(a0.w + b0.w + f0.w, 0.f);
    h[4] = fmaxf(a1.x + b1.x + f1.x, 0.f); h[5] = fmaxf(a1.y + b1.y + f1.y, 0.f);
    h[6] = fmaxf(a1.z + b1.z + f1.z, 0.f); h[7] = fmaxf(a1.w + b1.w + f1.w, 0.f);
    bf16x8 o;
    float s = 0.f;
    #pragma unroll
    for (int i = 0; i < 8; ++i) { o[i] = (short)f2bf(h[i]); s += h[i] * h[i]; }
    *(bf16x8*)&hb[(size_t)row * NH + c0] = o;
    #pragma unroll
    for (int off = 32; off > 0; off >>= 1) s += __shfl_xor(s, off);
    if (lane == 0) hsq[row] = s;
}

// ---------------- GEMM2 + distance + t ----------------
// 256 threads = 4 waves 2x2; tile 128x128; wave-tile 64x64 (acc 4x4).
// BK=64, A+B LDS double-buffered, one barrier per iter (8 iters).
__global__ __launch_bounds__(256, 2) void gemm2_kernel(const unsigned short* __restrict__ hb,
                                                       const unsigned short* __restrict__ wqb,
                                                       const float* __restrict__ hsq,
                                                       const float* __restrict__ wqsq,
                                                       float* __restrict__ out) {
    __shared__ unsigned short As[2 * 128 * 64];   // 32 KiB
    __shared__ unsigned short Bs[2 * 128 * 64];   // 32 KiB

    const int tid = threadIdx.x;
    const int lane = tid & 63;
    const int wave = tid >> 6;
    const int wm = wave >> 1, wn = wave & 1;
    const int quad = lane >> 4;
    const int r = lane & 15;

    // bid = 64a + 8b + c -> m-tile = 8c + a (0..63), n-tile = b (0..7)
    const int bid = blockIdx.x;                   // 0..511
    const int n0 = ((bid >> 3) & 7) * 128;
    const int m0 = (((bid & 7) << 3) | (bid >> 6)) * 128;

    f32x4 acc[4][4];
    #pragma unroll
    for (int i = 0; i < 4; ++i)
        #pragma unroll
        for (int j = 0; j < 4; ++j) acc[i][j] = (f32x4)(0.0f);

    const int lrow = lane >> 3;
    const int gch = (lane & 7) ^ lrow;
    const char* hbB = (const char*)hb;
    const char* wqB = (const char*)wqb;
    char* AsB = (char*)As;
    char* BsB = (char*)Bs;
    const int xk = r & 7;

    auto stage = [&](int buf, int k0) {
        #pragma unroll
        for (int c = 0; c < 4; ++c) {
            int R0 = wave * 32 + c * 8;
            glld16(hbB + (size_t)(m0 + R0 + lrow) * (NH * 2) + k0 * 2 + gch * 16,
                   AsB + buf * 16384 + R0 * 128);
            glld16(wqB + (size_t)(n0 + R0 + lrow) * (NH * 2) + k0 * 2 + gch * 16,
                   BsB + buf * 16384 + R0 * 128);
        }
    };

    stage(0, 0);
    #pragma unroll 1
    for (int it = 0; it < NH / 64; ++it) {
        const int k0 = it * 64;
        __syncthreads();
        if (it + 1 < NH / 64) stage((it + 1) & 1, k0 + 64);
        const char* ap = AsB + (it & 1) * 16384 + (wm * 64 + r) * 128;
        const char* bp = BsB + (it & 1) * 16384 + (wn * 64 + r) * 128;
        #pragma unroll
        for (int s = 0; s < 2; ++s) {
            const int ch = ((s * 4 + quad) ^ xk) * 16;
            bf16x8 af[4], bfv[4];
            #pragma unroll
            for (int i = 0; i < 4; ++i) af[i] = *(const bf16x8*)(ap + i * 16 * 128 + ch);
            #pragma unroll
            for (int j = 0; j < 4; ++j) bfv[j] = *(const bf16x8*)(bp + j * 16 * 128 + ch);
            #pragma unroll
            for (int i = 0; i < 4; ++i)
                #pragma unroll
                for (int j = 0; j < 4; ++j)
                    acc[i][j] = __builtin_amdgcn_mfma_f32_16x16x32_bf16(af[i], bfv[j], acc[i][j], 0, 0, 0);
        }
    }

    float hs[4][4];
    #pragma unroll
    for (int i = 0; i < 4; ++i)
        #pragma unroll
        for (int rr = 0; rr < 4; ++rr)
            hs[i][rr] = hsq[m0 + wm * 64 + i * 16 + quad * 4 + rr];

    #pragma unroll
    for (int i = 0; i < 4; ++i) {
        #pragma unroll
        for (int j = 0; j < 4; ++j) {
            int col = n0 + wn * 64 + j * 16 + r;
            float wq = wqsq[col];
            #pragma unroll
            for (int rr = 0; rr < 4; ++rr) {
                int row = m0 + wm * 64 + i * 16 + quad * 4 + rr;
                float d = hs[i][rr] - 2.0f * acc[i][j][rr] + wq;
                d = fmaxf(d, 0.0f);
                out[(size_t)row * NY + col] = -__logf(1.0f + d);
            }
        }
    }
}

// ---------------- per-row logsumexp (no max pass: t <= 0 so exp is safe) ----------------
__global__ __launch_bounds__(256) void lse_kernel(float* __restrict__ out) {
    __shared__ float reds[4];
    const int tid = threadIdx.x;
    const int lane = tid & 63;
    const int wave = tid >> 6;
    float* p = out + (size_t)blockIdx.x * NY;
    float4 v = ((const float4*)p)[tid];
    float s = __expf(v.x) + __expf(v.y) + __expf(v.z) + __expf(v.w);
    #pragma unroll
    for (int off = 32; off > 0; off >>= 1) s += __shfl_xor(s, off);
    if (lane == 0) reds[wave] = s;
    __syncthreads();
    float lse = __logf(reds[0] + reds[1] + reds[2] + reds[3]);
    v.x -= lse; v.y -= lse; v.z -= lse; v.w -= lse;
    ((float4*)p)[tid] = v;
}

extern "C" void kernel_launch(void* const* d_in, const int* in_sizes, int n_in,
                              void* d_out, int out_size, void* d_ws, size_t ws_size,
                              hipStream_t stream) {
    const float* x    = (const float*)d_in[0];
    const float* W_fc = (const float*)d_in[1];
    const float* b_fc = (const float*)d_in[2];
    const float* W_q  = (const float*)d_in[3];
    float* out = (float*)d_out;

    char* ws = (char*)d_ws;
    unsigned short* xb   = (unsigned short*)(ws);                        // 32 MiB
    unsigned short* wfcb = (unsigned short*)(ws + 33554432);             // 2 MiB
    unsigned short* wqb  = (unsigned short*)(ws + 35651584);             // 1 MiB
    float*          wqsq = (float*)(ws + 36700160);                      // 4 KiB
    unsigned short* hb   = (unsigned short*)(ws + 36704256);             // 8 MiB
    float*          hsq  = (float*)(ws + 45092864);                      // 32 KiB

    // d_out doubles as fp32 split-K partial scratch (2 x 8192 x 512 fp32 = out_size)
    float* partial = out;

    prep_kernel<<<EW_BLOCKS + WQ_BLOCKS, 256, 0, stream>>>(x, W_fc, W_q, xb, wfcb, wqb, wqsq);
    gemm1_kernel<<<512, 256, 0, stream>>>(xb, wfcb, partial);
    reduce_kernel<<<B_ROWS / 4, 256, 0, stream>>>(partial, b_fc, hb, hsq);
    gemm2_kernel<<<512, 256, 0, stream>>>(hb, wqb, hsq, wqsq, out);
    lse_kernel<<<B_ROWS, 256, 0, stream>>>(out);
}

// Round 6
// 166.484 us; speedup vs baseline: 1.1616x; 1.0184x over previous
//
#include <hip/hip_runtime.h>
#include <stdint.h>
#include <stddef.h>

#define B_ROWS 8192
#define NX 2048
#define NH 512
#define NY 1024

// prep kernel block split: elementwise cast blocks, then wq blocks
#define X_ELEMS (B_ROWS * NX)                 // 16777216 (relu+cast)
#define EW_ELEMS (X_ELEMS + NH * NX)          // + 1048576 (plain cast)
#define EW_BLOCKS (EW_ELEMS / (8 * 256))      // 8704
#define WQ_BLOCKS (NY / 4)                    // 256

typedef __attribute__((ext_vector_type(8))) short bf16x8;
typedef __attribute__((ext_vector_type(4))) float f32x4;

static __device__ __forceinline__ unsigned short f2bf(float f) {
    union { float f; unsigned int u; } c; c.f = f;
    unsigned int r = 0x7FFFu + ((c.u >> 16) & 1u);
    return (unsigned short)((c.u + r) >> 16);
}

static __device__ __forceinline__ void glld16(const void* g, void* l) {
    __builtin_amdgcn_global_load_lds(
        (const __attribute__((address_space(1))) unsigned int*)g,
        (__attribute__((address_space(3))) unsigned int*)l, 16, 0, 0);
}

// ---------------- prep: relu(x)->bf16, W_fc->bf16, W_q->bf16+rowsq, hsq=0 ----------------
__global__ __launch_bounds__(256) void prep_kernel(const float* __restrict__ x,
                                                   const float* __restrict__ wfc,
                                                   const float* __restrict__ wq,
                                                   unsigned short* __restrict__ xb,
                                                   unsigned short* __restrict__ wfcb,
                                                   unsigned short* __restrict__ wqb,
                                                   float* __restrict__ wqsq,
                                                   float* __restrict__ hsq) {
    const int bid = blockIdx.x;
    const int tid = threadIdx.x;
    if (bid < EW_BLOCKS) {
        size_t idx = ((size_t)bid * 256 + tid) * 8;
        if (idx < (size_t)X_ELEMS) {
            float4 a = *(const float4*)&x[idx];
            float4 b = *(const float4*)&x[idx + 4];
            bf16x8 o;
            o[0] = (short)f2bf(fmaxf(a.x, 0.f)); o[1] = (short)f2bf(fmaxf(a.y, 0.f));
            o[2] = (short)f2bf(fmaxf(a.z, 0.f)); o[3] = (short)f2bf(fmaxf(a.w, 0.f));
            o[4] = (short)f2bf(fmaxf(b.x, 0.f)); o[5] = (short)f2bf(fmaxf(b.y, 0.f));
            o[6] = (short)f2bf(fmaxf(b.z, 0.f)); o[7] = (short)f2bf(fmaxf(b.w, 0.f));
            *(bf16x8*)&xb[idx] = o;
        } else {
            size_t off = idx - X_ELEMS;
            float4 a = *(const float4*)&wfc[off];
            float4 b = *(const float4*)&wfc[off + 4];
            bf16x8 o;
            o[0] = (short)f2bf(a.x); o[1] = (short)f2bf(a.y);
            o[2] = (short)f2bf(a.z); o[3] = (short)f2bf(a.w);
            o[4] = (short)f2bf(b.x); o[5] = (short)f2bf(b.y);
            o[6] = (short)f2bf(b.z); o[7] = (short)f2bf(b.w);
            *(bf16x8*)&wfcb[off] = o;
        }
    } else {
        const int b2 = bid - EW_BLOCKS;        // 0..255
        const int lane = tid & 63;
        const int row = b2 * 4 + (tid >> 6);
        const float* p = wq + (size_t)row * NH + lane * 8;
        float4 a = *(const float4*)p;
        float4 b = *(const float4*)(p + 4);
        bf16x8 o;
        o[0] = (short)f2bf(a.x); o[1] = (short)f2bf(a.y);
        o[2] = (short)f2bf(a.z); o[3] = (short)f2bf(a.w);
        o[4] = (short)f2bf(b.x); o[5] = (short)f2bf(b.y);
        o[6] = (short)f2bf(b.z); o[7] = (short)f2bf(b.w);
        *(bf16x8*)&wqb[(size_t)row * NH + lane * 8] = o;
        float s = a.x*a.x + a.y*a.y + a.z*a.z + a.w*a.w
                + b.x*b.x + b.y*b.y + b.z*b.z + b.w*b.w;
        #pragma unroll
        for (int off = 32; off > 0; off >>= 1) s += __shfl_xor(s, off);
        if (lane == 0) wqsq[row] = s;
        if (tid < 32) hsq[b2 * 32 + tid] = 0.0f;   // zero-init for gemm1 atomics
    }
}

// ---------------- GEMM1: h = relu(xb @ wfcb^T + b) -> bf16 hb, fused hsq ----------------
// 512 threads = 2 k-groups x 4 waves (2x2). Tile 128(M)x128(N); wave-tile 64x64.
// In-block split-K: group g covers k in [g*1024, g*1024+1024), BK=32, double-buffered
// LDS (one barrier per iter). Epilogue: group1 dumps acc to (reused) LDS, group0
// combines + bias + relu + f2bf + hsq (shuffle+atomic).
// LDS rows are 64 B; store-side chunk swizzle f(row)=(row>>1)&3 keeps all
// b128 reads <=2-way (free).
__global__ __launch_bounds__(512, 2) void gemm1_kernel(const unsigned short* __restrict__ xb,
                                                       const unsigned short* __restrict__ wfcb,
                                                       const float* __restrict__ b_fc,
                                                       unsigned short* __restrict__ hb,
                                                       float* __restrict__ hsq) {
    __shared__ unsigned char smem[65536];
    unsigned char* AsB = smem;             // [g][buf][128 rows][32 k] bf16 = 4 x 8 KiB
    unsigned char* BsB = smem + 32768;

    const int tid = threadIdx.x;
    const int lane = tid & 63;
    const int grp = tid >> 8;              // k-half 0/1
    const int wave = (tid >> 6) & 3;       // wave within group
    const int wm = wave >> 1, wn = wave & 1;
    const int quad = lane >> 4;
    const int r = lane & 15;

    // bid = c + 8n + 32h : mtile = 8c + h (0..63), ntile = n (0..3); c = XCD slot
    const int bid = blockIdx.x;            // 0..255
    const int n0 = ((bid >> 3) & 3) * 128;
    const int m0 = (((bid & 7) << 3) | (bid >> 5)) * 128;
    const int kbase = grp * (NX / 2);

    f32x4 acc[4][4];
    #pragma unroll
    for (int i = 0; i < 4; ++i)
        #pragma unroll
        for (int j = 0; j < 4; ++j) acc[i][j] = (f32x4)(0.0f);

    const int lrow = lane >> 2;                       // 0..15 (row within 16-row chunk)
    const int gch = (lane & 3) ^ ((lrow >> 1) & 3);   // swizzled 16B chunk
    const char* xbB = (const char*)xb;
    const char* wfB = (const char*)wfcb;
    const int fsw = (quad ^ ((r >> 1) & 3)) * 16;     // fragment chunk byte offset

    auto stage = [&](int buf, int k0) {
        const int sb = grp * 16384 + buf * 8192;
        #pragma unroll
        for (int c = 0; c < 2; ++c) {
            int R0 = wave * 32 + c * 16;
            glld16(xbB + (size_t)(m0 + R0 + lrow) * (NX * 2) + k0 * 2 + gch * 16,
                   AsB + sb + R0 * 64);
            glld16(wfB + (size_t)(n0 + R0 + lrow) * (NX * 2) + k0 * 2 + gch * 16,
                   BsB + sb + R0 * 64);
        }
    };

    stage(0, kbase);
    #pragma unroll 1
    for (int it = 0; it < 32; ++it) {
        __syncthreads();
        if (it + 1 < 32) stage((it + 1) & 1, kbase + it * 32 + 32);
        const unsigned char* ab = AsB + grp * 16384 + (it & 1) * 8192;
        const unsigned char* bb = BsB + grp * 16384 + (it & 1) * 8192;
        bf16x8 af[4], bfv[4];
        #pragma unroll
        for (int i = 0; i < 4; ++i)
            af[i] = *(const bf16x8*)(ab + (wm * 64 + i * 16 + r) * 64 + fsw);
        #pragma unroll
        for (int j = 0; j < 4; ++j)
            bfv[j] = *(const bf16x8*)(bb + (wn * 64 + j * 16 + r) * 64 + fsw);
        #pragma unroll
        for (int i = 0; i < 4; ++i)
            #pragma unroll
            for (int j = 0; j < 4; ++j)
                acc[i][j] = __builtin_amdgcn_mfma_f32_16x16x32_bf16(af[i], bfv[j], acc[i][j], 0, 0, 0);
    }

    // ---- combine the two k-halves through LDS, epilogue by group 0 ----
    float* smemF = (float*)smem;
    __syncthreads();
    if (grp == 1) {
        #pragma unroll
        for (int i = 0; i < 4; ++i) {
            #pragma unroll
            for (int j = 0; j < 4; ++j) {
                int cl = wn * 64 + j * 16 + r;
                int rowb = wm * 64 + i * 16 + quad * 4;
                *(f32x4*)(smemF + cl * 128 + (rowb ^ ((cl & 7) << 2))) = acc[i][j];
            }
        }
    }
    __syncthreads();
    if (grp == 0) {
        float p[4][4];
        #pragma unroll
        for (int i = 0; i < 4; ++i)
            #pragma unroll
            for (int rr = 0; rr < 4; ++rr) p[i][rr] = 0.0f;

        #pragma unroll
        for (int i = 0; i < 4; ++i) {
            #pragma unroll
            for (int j = 0; j < 4; ++j) {
                int cl = wn * 64 + j * 16 + r;
                int rowb = wm * 64 + i * 16 + quad * 4;
                f32x4 o = *(const f32x4*)(smemF + cl * 128 + (rowb ^ ((cl & 7) << 2)));
                int col = n0 + cl;
                float bias = b_fc[col];
                #pragma unroll
                for (int rr = 0; rr < 4; ++rr) {
                    float v = fmaxf(acc[i][j][rr] + o[rr] + bias, 0.0f);
                    hb[(size_t)(m0 + rowb + rr) * NH + col] = f2bf(v);
                    p[i][rr] += v * v;
                }
            }
        }
        #pragma unroll
        for (int mask = 1; mask < 16; mask <<= 1) {
            #pragma unroll
            for (int i = 0; i < 4; ++i)
                #pragma unroll
                for (int rr = 0; rr < 4; ++rr)
                    p[i][rr] += __shfl_xor(p[i][rr], mask);
        }
        if (r == 0) {
            #pragma unroll
            for (int i = 0; i < 4; ++i)
                #pragma unroll
                for (int rr = 0; rr < 4; ++rr)
                    atomicAdd(&hsq[m0 + wm * 64 + i * 16 + quad * 4 + rr], p[i][rr]);
        }
    }
}

// ---------------- GEMM2 + distance + t ----------------
// 256 threads = 4 waves 2x2; tile 128x128; wave-tile 64x64 (acc 4x4).
// BK=64, A+B LDS double-buffered, one barrier per iter (8 iters).
__global__ __launch_bounds__(256, 2) void gemm2_kernel(const unsigned short* __restrict__ hb,
                                                       const unsigned short* __restrict__ wqb,
                                                       const float* __restrict__ hsq,
                                                       const float* __restrict__ wqsq,
                                                       float* __restrict__ out) {
    __shared__ unsigned short As[2 * 128 * 64];   // 32 KiB
    __shared__ unsigned short Bs[2 * 128 * 64];   // 32 KiB

    const int tid = threadIdx.x;
    const int lane = tid & 63;
    const int wave = tid >> 6;
    const int wm = wave >> 1, wn = wave & 1;
    const int quad = lane >> 4;
    const int r = lane & 15;

    // bid = 64a + 8b + c -> m-tile = 8c + a (0..63), n-tile = b (0..7)
    const int bid = blockIdx.x;                   // 0..511
    const int n0 = ((bid >> 3) & 7) * 128;
    const int m0 = (((bid & 7) << 3) | (bid >> 6)) * 128;

    f32x4 acc[4][4];
    #pragma unroll
    for (int i = 0; i < 4; ++i)
        #pragma unroll
        for (int j = 0; j < 4; ++j) acc[i][j] = (f32x4)(0.0f);

    const int lrow = lane >> 3;
    const int gch = (lane & 7) ^ lrow;
    const char* hbB = (const char*)hb;
    const char* wqB = (const char*)wqb;
    char* AsB = (char*)As;
    char* BsB = (char*)Bs;
    const int xk = r & 7;

    auto stage = [&](int buf, int k0) {
        #pragma unroll
        for (int c = 0; c < 4; ++c) {
            int R0 = wave * 32 + c * 8;
            glld16(hbB + (size_t)(m0 + R0 + lrow) * (NH * 2) + k0 * 2 + gch * 16,
                   AsB + buf * 16384 + R0 * 128);
            glld16(wqB + (size_t)(n0 + R0 + lrow) * (NH * 2) + k0 * 2 + gch * 16,
                   BsB + buf * 16384 + R0 * 128);
        }
    };

    stage(0, 0);
    #pragma unroll 1
    for (int it = 0; it < NH / 64; ++it) {
        const int k0 = it * 64;
        __syncthreads();
        if (it + 1 < NH / 64) stage((it + 1) & 1, k0 + 64);
        const char* ap = AsB + (it & 1) * 16384 + (wm * 64 + r) * 128;
        const char* bp = BsB + (it & 1) * 16384 + (wn * 64 + r) * 128;
        #pragma unroll
        for (int s = 0; s < 2; ++s) {
            const int ch = ((s * 4 + quad) ^ xk) * 16;
            bf16x8 af[4], bfv[4];
            #pragma unroll
            for (int i = 0; i < 4; ++i) af[i] = *(const bf16x8*)(ap + i * 16 * 128 + ch);
            #pragma unroll
            for (int j = 0; j < 4; ++j) bfv[j] = *(const bf16x8*)(bp + j * 16 * 128 + ch);
            #pragma unroll
            for (int i = 0; i < 4; ++i)
                #pragma unroll
                for (int j = 0; j < 4; ++j)
                    acc[i][j] = __builtin_amdgcn_mfma_f32_16x16x32_bf16(af[i], bfv[j], acc[i][j], 0, 0, 0);
        }
    }

    float hs[4][4];
    #pragma unroll
    for (int i = 0; i < 4; ++i)
        #pragma unroll
        for (int rr = 0; rr < 4; ++rr)
            hs[i][rr] = hsq[m0 + wm * 64 + i * 16 + quad * 4 + rr];

    #pragma unroll
    for (int i = 0; i < 4; ++i) {
        #pragma unroll
        for (int j = 0; j < 4; ++j) {
            int col = n0 + wn * 64 + j * 16 + r;
            float wq = wqsq[col];
            #pragma unroll
            for (int rr = 0; rr < 4; ++rr) {
                int row = m0 + wm * 64 + i * 16 + quad * 4 + rr;
                float d = hs[i][rr] - 2.0f * acc[i][j][rr] + wq;
                d = fmaxf(d, 0.0f);
                out[(size_t)row * NY + col] = -__logf(1.0f + d);
            }
        }
    }
}

// ---------------- per-row logsumexp (no max pass: t <= 0 so exp is safe) ----------------
__global__ __launch_bounds__(256) void lse_kernel(float* __restrict__ out) {
    __shared__ float reds[4];
    const int tid = threadIdx.x;
    const int lane = tid & 63;
    const int wave = tid >> 6;
    float* p = out + (size_t)blockIdx.x * NY;
    float4 v = ((const float4*)p)[tid];
    float s = __expf(v.x) + __expf(v.y) + __expf(v.z) + __expf(v.w);
    #pragma unroll
    for (int off = 32; off > 0; off >>= 1) s += __shfl_xor(s, off);
    if (lane == 0) reds[wave] = s;
    __syncthreads();
    float lse = __logf(reds[0] + reds[1] + reds[2] + reds[3]);
    v.x -= lse; v.y -= lse; v.z -= lse; v.w -= lse;
    ((float4*)p)[tid] = v;
}

extern "C" void kernel_launch(void* const* d_in, const int* in_sizes, int n_in,
                              void* d_out, int out_size, void* d_ws, size_t ws_size,
                              hipStream_t stream) {
    const float* x    = (const float*)d_in[0];
    const float* W_fc = (const float*)d_in[1];
    const float* b_fc = (const float*)d_in[2];
    const float* W_q  = (const float*)d_in[3];
    float* out = (float*)d_out;

    char* ws = (char*)d_ws;
    unsigned short* xb   = (unsigned short*)(ws);                        // 32 MiB
    unsigned short* wfcb = (unsigned short*)(ws + 33554432);             // 2 MiB
    unsigned short* wqb  = (unsigned short*)(ws + 35651584);             // 1 MiB
    float*          wqsq = (float*)(ws + 36700160);                      // 4 KiB
    unsigned short* hb   = (unsigned short*)(ws + 36704256);             // 8 MiB
    float*          hsq  = (float*)(ws + 45092864);                      // 32 KiB

    prep_kernel<<<EW_BLOCKS + WQ_BLOCKS, 256, 0, stream>>>(x, W_fc, W_q, xb, wfcb, wqb, wqsq, hsq);
    gemm1_kernel<<<256, 512, 0, stream>>>(xb, wfcb, b_fc, hb, hsq);
    gemm2_kernel<<<512, 256, 0, stream>>>(hb, wqb, hsq, wqsq, out);
    lse_kernel<<<B_ROWS, 256, 0, stream>>>(out);
}